// Round 16
// baseline (545.114 us; speedup 1.0000x reference)
//
#include <hip/hip_runtime.h>
#include <math.h>

#define LTOT 5376

typedef __attribute__((ext_vector_type(8))) __bf16 bf16x8;
typedef __attribute__((ext_vector_type(4))) float f32x4;
typedef __attribute__((ext_vector_type(8))) unsigned short us8;
typedef __attribute__((ext_vector_type(4))) unsigned short us4;

static __device__ __forceinline__ float4 ld4(const float* p) { return *(const float4*)p; }

static __device__ __forceinline__ unsigned short f2bf(float f) {
    unsigned int u = __float_as_uint(f);
    return (unsigned short)((u + 0x7fffu + ((u >> 16) & 1u)) >> 16);
}
static __device__ __forceinline__ float bf2f(unsigned short s) {
    return __uint_as_float(((unsigned int)s) << 16);
}

// async global->LDS, 16B per lane; lds base wave-uniform (HW adds lane*16)
static __device__ __forceinline__ void gl16(const unsigned short* g, unsigned short* l) {
    __builtin_amdgcn_global_load_lds(
        (const __attribute__((address_space(1))) unsigned int*)g,
        (__attribute__((address_space(3))) unsigned int*)l, 16, 0, 0);
}

// ================= bf16 MFMA GEMM core, 3-buffer counted-vmcnt pipeline =================
__device__ __forceinline__ void gemm_core(
    const unsigned short* __restrict__ A,
    const unsigned short* __restrict__ B,
    const float* __restrict__ bias,
    float* __restrict__ C1, unsigned short* __restrict__ C2,
    const float* __restrict__ posf, unsigned short* __restrict__ qb,
    unsigned short* As, unsigned short* Bs,     // each 3*4096 shorts
    int m0, int mo0, int n0, int N, int Kloop, int ldk, int omode, int relu)
{
    const int tid  = threadIdx.x;
    const int wave = tid >> 6;
    const int lane = tid & 63;
    const int wm   = (wave >> 1) * 32;
    const int wn   = (wave & 1) * 32;
    const int fr   = lane & 15;
    const int ko   = lane >> 4;

    const int q0 = tid, q1 = tid + 256;
    const int r0 = q0 >> 3, c0v = (q0 & 7) ^ (r0 & 7);
    const int r1 = q1 >> 3, c1v = (q1 & 7) ^ (r1 & 7);
    const unsigned short* a0 = A + (size_t)(m0 + r0) * ldk + (c0v << 3);
    const unsigned short* a1 = A + (size_t)(m0 + r1) * ldk + (c1v << 3);
    int bn0 = n0 + r0; if (bn0 > N - 1) bn0 = N - 1;
    int bn1 = n0 + r1; if (bn1 > N - 1) bn1 = N - 1;
    const unsigned short* b0 = B + (size_t)bn0 * ldk + (c0v << 3);
    const unsigned short* b1 = B + (size_t)bn1 * ldk + (c1v << 3);
    const int wb = wave << 9;

    f32x4 acc[2][2] = {};
    const int nt = Kloop >> 6;

    auto stage = [&](int buf, int t) {
        const int kof = t << 6;
        gl16(a0 + kof, As + buf * 4096 + wb);
        gl16(a1 + kof, As + buf * 4096 + 2048 + wb);
        gl16(b0 + kof, Bs + buf * 4096 + wb);
        gl16(b1 + kof, Bs + buf * 4096 + 2048 + wb);
    };

    stage(0, 0);
    stage(1, 1);
    asm volatile("s_waitcnt vmcnt(4)" ::: "memory");
    __builtin_amdgcn_s_barrier();
    __builtin_amdgcn_sched_barrier(0);

    for (int t = 0; t < nt; t++) {
        if (t + 2 < nt) stage((t + 2) % 3, t + 2);
        const unsigned short* Ab = As + (t % 3) * 4096;
        const unsigned short* Bb = Bs + (t % 3) * 4096;
        #pragma unroll
        for (int sub = 0; sub < 2; sub++) {
            bf16x8 af[2], bfr[2];
            const int kk = (sub << 2) + ko;
            #pragma unroll
            for (int i = 0; i < 2; i++) {
                int r = wm + i * 16 + fr;
                af[i] = *(const bf16x8*)&Ab[(r << 6) + ((kk ^ (r & 7)) << 3)];
                int c = wn + i * 16 + fr;
                bfr[i] = *(const bf16x8*)&Bb[(c << 6) + ((kk ^ (c & 7)) << 3)];
            }
            #pragma unroll
            for (int i = 0; i < 2; i++)
                #pragma unroll
                for (int j = 0; j < 2; j++)
                    acc[i][j] = __builtin_amdgcn_mfma_f32_16x16x32_bf16(af[i], bfr[j], acc[i][j], 0, 0, 0);
        }
        if (t + 1 < nt) {
            if (t + 2 < nt) asm volatile("s_waitcnt vmcnt(4) lgkmcnt(0)" ::: "memory");
            else            asm volatile("s_waitcnt vmcnt(0) lgkmcnt(0)" ::: "memory");
            __builtin_amdgcn_s_barrier();
            __builtin_amdgcn_sched_barrier(0);
        }
    }

    #pragma unroll
    for (int j = 0; j < 2; j++) {
        int col = n0 + wn + j * 16 + fr;
        if (col >= N) continue;
        float cb = bias[col];
        #pragma unroll
        for (int i = 0; i < 2; i++) {
            #pragma unroll
            for (int r = 0; r < 4; r++) {
                int row = mo0 + wm + i * 16 + ko * 4 + r;
                float v = acc[i][j][r] + cb;
                if (relu) v = fmaxf(v, 0.f);
                size_t off = (size_t)row * N + col;
                if (omode == 0)      C1[off] = v;
                else if (omode == 1) C2[off] = f2bf(v);
                else if (omode == 2) { C1[off] = v; C2[off] = f2bf(v); }
                else { C1[off] = v; C2[off] = f2bf(v); qb[off] = f2bf(v + posf[off]); }
            }
        }
    }
}

// generic wrapper
__global__ __launch_bounds__(256) void bgemm_k(
    const unsigned short* __restrict__ A, const unsigned short* __restrict__ B,
    const float* __restrict__ bias, float* __restrict__ C1, unsigned short* __restrict__ C2,
    int N, int K, int omode, int relu)
{
    __shared__ unsigned short As[3 * 4096], Bs[3 * 4096];
    int m = blockIdx.y * 64;
    gemm_core(A, B, bias, C1, C2, nullptr, nullptr, As, Bs, m, m, blockIdx.x * 64, N, K, K, omode, relu);
}

// split-K (2-way) f32-out GEMM: kpart=blockIdx.z; partials to C0 / C1p
__global__ __launch_bounds__(256) void bgemmsk_k(
    const unsigned short* __restrict__ A, const unsigned short* __restrict__ B,
    const float* __restrict__ bias, const float* __restrict__ zbuf,
    float* __restrict__ C0, float* __restrict__ C1p, int N, int fullK)
{
    __shared__ unsigned short As[3 * 4096], Bs[3 * 4096];
    const int m = blockIdx.y * 64;
    const int kp = blockIdx.z;
    const int Ks = fullK >> 1;
    gemm_core(A + kp * Ks, B + kp * Ks, kp ? zbuf : bias,
              kp ? C1p : C0, nullptr, nullptr, nullptr,
              As, Bs, m, m, blockIdx.x * 64, N, Ks, fullK, 0, 0);
}

// per-layer head: oa-gemm split-K (kp0 -> oab, kp1 -> oab2) + vp-gemm full-K -> valb
// grid (14, 84): bx<5 oa kp0, bx<10 oa kp1, else vp
__global__ __launch_bounds__(256) void oavp_k(
    const unsigned short* __restrict__ qbb, const unsigned short* __restrict__ woa,
    const float* __restrict__ boa, const float* __restrict__ zbuf,
    float* __restrict__ oab, float* __restrict__ oab2,
    const unsigned short* __restrict__ srcb, const unsigned short* __restrict__ wvp,
    const float* __restrict__ bvp, unsigned short* __restrict__ valb)
{
    __shared__ unsigned short As[3 * 4096], Bs[3 * 4096];
    const int bx = blockIdx.x;
    const int m = blockIdx.y * 64;
    if (bx < 5)
        gemm_core(qbb,       woa,       boa,  oab,  nullptr, nullptr, nullptr, As, Bs, m, m, bx * 64, 288, 128, 256, 0, 0);
    else if (bx < 10)
        gemm_core(qbb + 128, woa + 128, zbuf, oab2, nullptr, nullptr, nullptr, As, Bs, m, m, (bx - 5) * 64, 288, 128, 256, 0, 0);
    else
        gemm_core(srcb, wvp, bvp, nullptr, valb, nullptr, nullptr, As, Bs, m, m, (bx - 10) * 64, 256, 256, 256, 1, 0);
}

// fused input projections (3 levels, different K) + qbb = src + pos epilogue
__global__ __launch_bounds__(256) void inproj_k(
    const unsigned short* __restrict__ fT0, const unsigned short* __restrict__ w0, const float* __restrict__ b0,
    const unsigned short* __restrict__ fT1, const unsigned short* __restrict__ w1, const float* __restrict__ b1,
    const unsigned short* __restrict__ fT2, const unsigned short* __restrict__ w2, const float* __restrict__ b2,
    float* __restrict__ src, unsigned short* __restrict__ srcb,
    const float* __restrict__ posf, unsigned short* __restrict__ qbb)
{
    __shared__ unsigned short As[3 * 4096], Bs[3 * 4096];
    const int by = blockIdx.y;
    const int n0 = blockIdx.x * 64;
    if (by < 64)
        gemm_core(fT0, w0, b0, src, srcb, posf, qbb, As, Bs, by * 64, by * 64, n0, 256, 256, 256, 3, 0);
    else if (by < 80)
        gemm_core(fT1, w1, b1, src, srcb, posf, qbb, As, Bs, (by - 64) * 64, 4096 + (by - 64) * 64, n0, 256, 512, 512, 3, 0);
    else
        gemm_core(fT2, w2, b2, src, srcb, posf, qbb, As, Bs, (by - 80) * 64, 5120 + (by - 80) * 64, n0, 256, 1024, 1024, 3, 0);
}

// ===== merged setup kernel (pack_oa | wconv | cvtall | posenc | cvtT feat0/1/2) =====
__global__ __launch_bounds__(256) void setup_k(
    const float* __restrict__ off_w, const float* __restrict__ off_b,
    const float* __restrict__ aw_w,  const float* __restrict__ aw_b,
    unsigned short* __restrict__ w_oa, float* __restrict__ b_oa,
    const float* __restrict__ out_w, unsigned short* __restrict__ wcb,
    const float* __restrict__ s0, const float* __restrict__ s1,
    const float* __restrict__ s2, const float* __restrict__ s3,
    const float* __restrict__ s4, const float* __restrict__ s5,
    const float* __restrict__ s6, const float* __restrict__ s7,
    unsigned short* __restrict__ dcvt,
    float* __restrict__ pos,
    const float* __restrict__ f0, const float* __restrict__ f1, const float* __restrict__ f2,
    unsigned short* __restrict__ d0, unsigned short* __restrict__ d1, unsigned short* __restrict__ d2,
    float* __restrict__ zbuf)
{
    const int bid = blockIdx.x;
    const int tid = threadIdx.x;
    if (bid < 1728) {
        int idx = bid * 256 + tid;
        int i = idx / 73728;
        int r = idx - i * 73728;
        int n = r >> 8;
        int k = r & 255;
        float v = (n < 192) ? off_w[((size_t)i * 192 + n) * 256 + k]
                            : aw_w[((size_t)i * 96 + (n - 192)) * 256 + k];
        w_oa[idx] = f2bf(v);
        if (k == 0)
            b_oa[i * 288 + n] = (n < 192) ? off_b[i * 192 + n] : aw_b[i * 96 + (n - 192)];
        if (bid == 0) { zbuf[tid] = 0.f; zbuf[256 + tid] = 0.f; }
    } else if (bid < 8640) {
        int idx = (bid - 1728) * 256 + tid;
        int c   = idx / 589824;
        int r   = idx - c * 589824;
        int icc = r / 73728;
        int r2  = r - icc * 73728;
        int oc  = r2 / 288;
        int r3  = r2 - oc * 288;
        int tap = r3 >> 5;
        int sl  = r3 & 31;
        int ic  = icc * 32 + (((sl >> 3) ^ ((oc >> 1) & 3)) << 3) + (sl & 7);
        wcb[idx] = f2bf(out_w[(((size_t)(c * 256 + oc)) * 256 + ic) * 9 + tap]);
    } else if (bid < 12992) {
        int i = (bid - 8640) * 256 + tid;
        const float* s; int off;
        if      (i <   98304) { s = s0; off = 0; }
        else if (i <  196608) { s = s1; off = 98304; }
        else if (i <  589824) { s = s2; off = 196608; }
        else if (i <  983040) { s = s3; off = 589824; }
        else if (i <  999424) { s = s4; off = 983040; }
        else if (i < 1032192) { s = s5; off = 999424; }
        else if (i < 1097728) { s = s6; off = 1032192; }
        else                  { s = s7; off = 1097728; }
        float4 v = ld4(&s[(size_t)(i - off) << 2]);
        us4 r = { f2bf(v.x), f2bf(v.y), f2bf(v.z), f2bf(v.w) };
        *(us4*)&dcvt[(size_t)i << 2] = r;
    } else if (bid < 15680) {
        int idx = (bid - 12992) * 256 + tid;
        int l = idx >> 7;
        int pr = idx & 127;
        int half = pr >> 6;
        int j = pr & 63;
        int HW, sh, p;
        if (l < 4096)      { HW = 64; sh = 6; p = l; }
        else if (l < 5120) { HW = 32; sh = 5; p = l - 4096; }
        else               { HW = 16; sh = 4; p = l - 5120; }
        int y = p >> sh;
        int x = p & (HW - 1);
        float invT = exp2f((float)j * (-13.287712379549449f / 64.f));
        float coord = (half == 0) ? (float)(y + 1) : (float)(x + 1);
        float v = coord / ((float)HW + 1e-6f) * 6.283185307179586f;
        float arg = v * invT;
        size_t base = (size_t)l * 256 + half * 128 + (j << 1);
        pos[base]     = sinf(arg);
        pos[base + 1] = cosf(arg);
    } else {
        __shared__ float t[32][33];
        int b = bid - 15680;
        const float* src; unsigned short* dst; int Ci, P, bx, by;
        if (b < 1024)      { src = f0; dst = d0; Ci = 256;  P = 4096; bx = b & 127;        by = b >> 7; }
        else if (b < 1536) { src = f1; dst = d1; Ci = 512;  P = 1024; bx = (b - 1024) & 31; by = (b - 1024) >> 5; }
        else               { src = f2; dst = d2; Ci = 1024; P = 256;  bx = (b - 1536) & 7;  by = (b - 1536) >> 3; }
        int c0 = by * 32, p0 = bx * 32;
        int x = tid & 31, y = tid >> 5;
        for (int i = y; i < 32; i += 8)
            t[i][x] = src[(size_t)(c0 + i) * P + p0 + x];
        __syncthreads();
        for (int i = y; i < 32; i += 8)
            dst[(size_t)(p0 + i) * Ci + c0 + x] = f2bf(t[x][i]);
    }
}

// ---------------- multi-scale deformable sampling, softmax fused ----------------
// 4 positions/block, 64 thr/pos; thread: 1 head x 4 channels (us4 gathers). grid 1344.
// Stages sum of two oa split-K partials (deterministic fixed-order add).
__global__ __launch_bounds__(256) void msdef_k(
    const unsigned short* __restrict__ valb,
    const float* __restrict__ oab, const float* __restrict__ oab2,
    unsigned short* __restrict__ out)
{
    __shared__ float sw[4 * 288];
    const int tid = threadIdx.x;
    const int bl = blockIdx.x;
    #pragma unroll
    for (int id = tid; id < 288; id += 256) {
        float4 v0 = ((const float4*)(oab  + (size_t)bl * 1152))[id];
        float4 v1 = ((const float4*)(oab2 + (size_t)bl * 1152))[id];
        v0.x += v1.x; v0.y += v1.y; v0.z += v1.z; v0.w += v1.w;
        ((float4*)sw)[id] = v0;
    }
    __syncthreads();

    const int p = tid >> 6;          // 0..3
    const int t = tid & 63;
    const int l = bl * 4 + p;
    const int h = t >> 3;            // 0..7
    const int co = (t & 7) << 2;     // 0,4,...,28
    const float* mo = sw + p * 288;

    float aw_r[12];
    {
        const float* sc = mo + 192 + h * 12;
        float mx = -1e30f;
        #pragma unroll
        for (int j = 0; j < 12; j++) { aw_r[j] = sc[j]; mx = fmaxf(mx, aw_r[j]); }
        float su = 0.f;
        #pragma unroll
        for (int j = 0; j < 12; j++) { aw_r[j] = expf(aw_r[j] - mx); su += aw_r[j]; }
        float inv = 1.f / su;
        #pragma unroll
        for (int j = 0; j < 12; j++) aw_r[j] *= inv;
    }

    float rx, ry;
    {
        int HW, sh, q;
        if (l < 4096)      { HW = 64; sh = 6; q = l; }
        else if (l < 5120) { HW = 32; sh = 5; q = l - 4096; }
        else               { HW = 16; sh = 4; q = l - 5120; }
        int y = q >> sh;
        int x = q & (HW - 1);
        rx = (x + 0.5f) / (float)HW;
        ry = (y + 0.5f) / (float)HW;
    }

    const int starts[3] = {0, 4096, 5120};
    const int dims[3]   = {64, 32, 16};
    float acc[4] = {};
    #pragma unroll
    for (int s = 0; s < 3; s++) {
        const int D = dims[s];
        const int st = starts[s];
        #pragma unroll
        for (int pt = 0; pt < 4; pt++) {
            float a  = aw_r[(s << 2) + pt];
            float px = rx * D + mo[h * 24 + (s << 3) + (pt << 1)]     - 0.5f;
            float py = ry * D + mo[h * 24 + (s << 3) + (pt << 1) + 1] - 0.5f;
            float x0f = floorf(px), y0f = floorf(py);
            float lx = px - x0f, ly = py - y0f;
            int x0 = (int)x0f, y0 = (int)y0f;
            float w00 = a * (1.f - lx) * (1.f - ly);
            float w10 = a * lx * (1.f - ly);
            float w01 = a * (1.f - lx) * ly;
            float w11 = a * lx * ly;
            #pragma unroll
            for (int cy = 0; cy < 2; cy++) {
                int yi = y0 + cy;
                if (yi < 0 || yi >= D) continue;
                #pragma unroll
                for (int cx = 0; cx < 2; cx++) {
                    int xi = x0 + cx;
                    if (xi < 0 || xi >= D) continue;
                    float w = cy ? (cx ? w11 : w01) : (cx ? w10 : w00);
                    us4 v = *(const us4*)&valb[((size_t)(st + yi * D + xi) << 8) + (h << 5) + co];
                    #pragma unroll
                    for (int e = 0; e < 4; e++)
                        acc[e] = fmaf(w, bf2f(v[e]), acc[e]);
                }
            }
        }
    }
    us4 r;
    #pragma unroll
    for (int e = 0; e < 4; e++) r[e] = f2bf(acc[e]);
    *(us4*)&out[((size_t)l << 8) + (h << 5) + co] = r;
}

// ---------------- layernorm (+2 residual partials), in-place fp32 + bf16 copy (+ q=out+pos) ----------------
template<bool HAS_POS>
__global__ __launch_bounds__(256) void ln_k(float* __restrict__ src, const float* __restrict__ add,
                                            const float* __restrict__ add2,
                                            const float* __restrict__ w, const float* __restrict__ b,
                                            unsigned short* __restrict__ outb,
                                            const float* __restrict__ posf,
                                            unsigned short* __restrict__ qbout)
{
    int row = blockIdx.x * 4 + (threadIdx.x >> 6);
    int lane = threadIdx.x & 63;
    size_t base = (size_t)row * 256 + (lane << 2);
    float4 x = ld4(&src[base]);
    float4 a = ld4(&add[base]);
    float4 a2 = ld4(&add2[base]);
    x.x += a.x + a2.x; x.y += a.y + a2.y; x.z += a.z + a2.z; x.w += a.w + a2.w;
    float s = x.x + x.y + x.z + x.w;
    #pragma unroll
    for (int o = 32; o > 0; o >>= 1) s += __shfl_xor(s, o, 64);
    float m = s * (1.f / 256.f);
    float d0 = x.x - m, d1 = x.y - m, d2 = x.z - m, d3 = x.w - m;
    float v = d0 * d0 + d1 * d1 + d2 * d2 + d3 * d3;
    #pragma unroll
    for (int o = 32; o > 0; o >>= 1) v += __shfl_xor(v, o, 64);
    float rs = rsqrtf(v * (1.f / 256.f) + 1e-5f);
    float4 wv = ld4(&w[lane << 2]);
    float4 bv = ld4(&b[lane << 2]);
    float4 o4;
    o4.x = d0 * rs * wv.x + bv.x;
    o4.y = d1 * rs * wv.y + bv.y;
    o4.z = d2 * rs * wv.z + bv.z;
    o4.w = d3 * rs * wv.w + bv.w;
    *(float4*)&src[base] = o4;
    us4 r = { f2bf(o4.x), f2bf(o4.y), f2bf(o4.z), f2bf(o4.w) };
    *(us4*)&outb[base] = r;
    if (HAS_POS) {
        float4 p4 = ld4(&posf[base]);
        us4 q = { f2bf(o4.x + p4.x), f2bf(o4.y + p4.y), f2bf(o4.z + p4.z), f2bf(o4.w + p4.w) };
        *(us4*)&qbout[base] = q;
    }
}

// ---------------- layer-5 ln2 + final fn layernorm fused (two LN passes) ----------------
__global__ __launch_bounds__(256) void ln2fn_k(float* __restrict__ src, const float* __restrict__ add,
                                               const float* __restrict__ add2,
                                               const float* __restrict__ w2, const float* __restrict__ b2,
                                               const float* __restrict__ wf, const float* __restrict__ bf,
                                               unsigned short* __restrict__ outb)
{
    int row = blockIdx.x * 4 + (threadIdx.x >> 6);
    int lane = threadIdx.x & 63;
    size_t base = (size_t)row * 256 + (lane << 2);
    float4 x = ld4(&src[base]);
    float4 a = ld4(&add[base]);
    float4 a2 = ld4(&add2[base]);
    x.x += a.x + a2.x; x.y += a.y + a2.y; x.z += a.z + a2.z; x.w += a.w + a2.w;
    // pass 1: n2
    float s = x.x + x.y + x.z + x.w;
    #pragma unroll
    for (int o = 32; o > 0; o >>= 1) s += __shfl_xor(s, o, 64);
    float m = s * (1.f / 256.f);
    float d0 = x.x - m, d1 = x.y - m, d2 = x.z - m, d3 = x.w - m;
    float v = d0 * d0 + d1 * d1 + d2 * d2 + d3 * d3;
    #pragma unroll
    for (int o = 32; o > 0; o >>= 1) v += __shfl_xor(v, o, 64);
    float rs = rsqrtf(v * (1.f / 256.f) + 1e-5f);
    float4 wv = ld4(&w2[lane << 2]);
    float4 bv = ld4(&b2[lane << 2]);
    float4 o4;
    o4.x = d0 * rs * wv.x + bv.x;
    o4.y = d1 * rs * wv.y + bv.y;
    o4.z = d2 * rs * wv.z + bv.z;
    o4.w = d3 * rs * wv.w + bv.w;
    // pass 2: fn
    float s2 = o4.x + o4.y + o4.z + o4.w;
    #pragma unroll
    for (int o = 32; o > 0; o >>= 1) s2 += __shfl_xor(s2, o, 64);
    float m2 = s2 * (1.f / 256.f);
    float e0 = o4.x - m2, e1 = o4.y - m2, e2 = o4.z - m2, e3 = o4.w - m2;
    float v2 = e0 * e0 + e1 * e1 + e2 * e2 + e3 * e3;
    #pragma unroll
    for (int o = 32; o > 0; o >>= 1) v2 += __shfl_xor(v2, o, 64);
    float rs2 = rsqrtf(v2 * (1.f / 256.f) + 1e-5f);
    float4 wf4 = ld4(&wf[lane << 2]);
    float4 bf4 = ld4(&bf[lane << 2]);
    float4 o5;
    o5.x = e0 * rs2 * wf4.x + bf4.x;
    o5.y = e1 * rs2 * wf4.y + bf4.y;
    o5.z = e2 * rs2 * wf4.z + bf4.z;
    o5.w = e3 * rs2 * wf4.w + bf4.w;
    *(float4*)&src[base] = o5;
    us4 r = { f2bf(o5.x), f2bf(o5.y), f2bf(o5.z), f2bf(o5.w) };
    *(us4*)&outb[base] = r;
}

// ===== tail: mems transposes (3 levels) + lateral 1x1 GEMM, one dispatch =====
__global__ __launch_bounds__(256) void tail_k(
    const float* __restrict__ src, float* __restrict__ outb_,
    const unsigned short* __restrict__ srcb, const unsigned short* __restrict__ w_lat,
    const float* __restrict__ lat_b, unsigned short* __restrict__ latb)
{
    if (blockIdx.x < 1344) {
        __shared__ float t[32][33];
        int b = blockIdx.x;
        int bx = b % 168, cy = b / 168;
        const float* s; float* d; int HW, p0;
        if (bx < 128)      { s = src;           d = outb_;           HW = 4096; p0 = bx * 32; }
        else if (bx < 160) { s = src + 1048576; d = outb_ + 1048576; HW = 1024; p0 = (bx - 128) * 32; }
        else               { s = src + 1310720; d = outb_ + 1310720; HW = 256;  p0 = (bx - 160) * 32; }
        int c0 = cy * 32;
        int x = threadIdx.x & 31, y = threadIdx.x >> 5;
        for (int i = y; i < 32; i += 8)
            t[i][x] = s[(size_t)(p0 + i) * 256 + c0 + x];
        __syncthreads();
        for (int i = y; i < 32; i += 8)
            d[(size_t)(c0 + i) * HW + p0 + x] = t[x][i];
    } else {
        __shared__ unsigned short As[3 * 4096], Bs[3 * 4096];
        int b = blockIdx.x - 1344;
        int m = (b >> 2) * 64;
        gemm_core(srcb, w_lat, lat_b, nullptr, latb, nullptr, nullptr, As, Bs,
                  m, m, (b & 3) * 64, 256, 256, 256, 1, 0);
    }
}

// ---------------- 3x3 conv via bf16 MFMA implicit GEMM, icc split-K (z=2) ----------------
__global__ __launch_bounds__(256) void conv3b_k(const unsigned short* __restrict__ inb,
                                                const unsigned short* __restrict__ wcb,
                                                float* __restrict__ out0,
                                                float* __restrict__ out1)
{
    __shared__ __align__(16) unsigned char smem[25344];
    unsigned short* sIn = (unsigned short*)smem;
    unsigned short* sW  = (unsigned short*)(smem + 6912);
    float* sO = (float*)smem;

    const int tid = threadIdx.x;
    const int mb = blockIdx.x;
    const int y0 = (mb >> 2) << 2;
    const int x0 = (mb & 3) << 4;
    const int oc0 = blockIdx.y << 5;
    const int icc0 = blockIdx.z << 2;
    float* out = blockIdx.z ? out1 : out0;
    const int wave = tid >> 6, lane = tid & 63;
    const int wm = (wave >> 1) * 32;
    const int wn = (wave & 1) * 16;
    const int fr = lane & 15, ko = lane >> 4;

    f32x4 acc[2] = {};

    for (int icc = icc0; icc < icc0 + 4; icc++) {
        __syncthreads();
        #pragma unroll
        for (int id = tid; id < 432; id += 256) {
            int pxi = id >> 2, ch = id & 3;
            int r = pxi / 18, s = pxi - r * 18;
            int gy = y0 - 1 + r, gx = x0 - 1 + s;
            us8 v = {};
            if (gy >= 0 && gy < 64 && gx >= 0 && gx < 64)
                v = *(const us8*)&inb[((size_t)(gy * 64 + gx) << 8) + (icc << 5) + (ch << 3)];
            *(us8*)&sIn[(pxi << 5) + ((ch ^ ((s >> 1) & 3)) << 3)] = v;
        }
        const unsigned short* wsrc = wcb + (((size_t)icc * 256 + oc0) * 9 << 5);
        #pragma unroll
        for (int id = tid; id < 1152; id += 256)
            *(us8*)&sW[id << 3] = *(const us8*)&wsrc[id << 3];
        __syncthreads();

        #pragma unroll
        for (int tap = 0; tap < 9; tap++) {
            const int ky = tap / 3, kx = tap - ky * 3;
            bf16x8 a[2], b;
            #pragma unroll
            for (int i = 0; i < 2; i++) {
                int px = wm + i * 16 + fr;
                int r = (px >> 4) + ky;
                int s = (px & 15) + kx;
                a[i] = *(const bf16x8*)&sIn[(((r * 18 + s)) << 5) + ((ko ^ ((s >> 1) & 3)) << 3)];
            }
            {
                int oc = wn + fr;
                b = *(const bf16x8*)&sW[(((oc * 9) + tap) << 5) + ((ko ^ ((oc >> 1) & 3)) << 3)];
            }
            #pragma unroll
            for (int i = 0; i < 2; i++)
                acc[i] = __builtin_amdgcn_mfma_f32_16x16x32_bf16(a[i], b, acc[i], 0, 0, 0);
        }
    }

    __syncthreads();
    #pragma unroll
    for (int i = 0; i < 2; i++) {
        int oc = wn + fr;
        int pxb = wm + i * 16 + ko * 4;
        *(f32x4*)&sO[oc * 68 + pxb] = acc[i];
    }
    __syncthreads();
    {
        int oc_r = tid >> 3;
        int yy   = (tid >> 1) & 3;
        int xh   = (tid & 1) << 3;
        float* dst = &out[(size_t)(oc0 + oc_r) * 4096 + (y0 + yy) * 64 + x0 + xh];
        const float* srcl = &sO[oc_r * 68 + yy * 16 + xh];
        *(float4*)&dst[0] = *(const float4*)&srcl[0];
        *(float4*)&dst[4] = *(const float4*)&srcl[4];
    }
}

// ---------------- groupnorm stage 1: per-slice partial stats (256 blocks) ----------------
__global__ __launch_bounds__(256) void gnstats2_k(const float* __restrict__ x0,
                                                  const float* __restrict__ x1,
                                                  float* __restrict__ st)
{
    const int g  = blockIdx.x >> 3;
    const int sl = blockIdx.x & 7;
    const float* p0 = x0 + (size_t)g * 32768 + sl * 4096;
    const float* p1 = x1 + (size_t)g * 32768 + sl * 4096;
    float s = 0.f, ss = 0.f;
    #pragma unroll
    for (int i = threadIdx.x * 4; i < 4096; i += 1024) {
        float4 v0 = ld4(&p0[i]);
        float4 v1 = ld4(&p1[i]);
        float e0 = v0.x + v1.x, e1 = v0.y + v1.y, e2 = v0.z + v1.z, e3 = v0.w + v1.w;
        s  += e0 + e1 + e2 + e3;
        ss += e0 * e0 + e1 * e1 + e2 * e2 + e3 * e3;
    }
    #pragma unroll
    for (int o = 32; o > 0; o >>= 1) {
        s  += __shfl_xor(s, o, 64);
        ss += __shfl_xor(ss, o, 64);
    }
    __shared__ float rs[4], rss[4];
    int wid = threadIdx.x >> 6;
    if ((threadIdx.x & 63) == 0) { rs[wid] = s; rss[wid] = ss; }
    __syncthreads();
    if (threadIdx.x == 0) {
        st[blockIdx.x * 2]     = rs[0] + rs[1] + rs[2] + rs[3];
        st[blockIdx.x * 2 + 1] = rss[0] + rss[1] + rss[2] + rss[3];
    }
}

// ---------------- groupnorm stage 2: apply + relu (1024 blocks) ----------------
template<int OUT>
__global__ __launch_bounds__(256) void gnapply2_k(const float* __restrict__ x0,
                                                  const float* __restrict__ x1,
                                                  const float* __restrict__ st,
                                                  const float* __restrict__ w, const float* __restrict__ b,
                                                  unsigned short* __restrict__ ob, float* __restrict__ of)
{
    int i = blockIdx.x * 256 + threadIdx.x;   // float4 index, 262144 total
    int c = i >> 10;
    int g = c >> 3;
    float S = 0.f, SS = 0.f;
    #pragma unroll
    for (int k = 0; k < 8; k++) {
        S  += st[(g * 8 + k) * 2];
        SS += st[(g * 8 + k) * 2 + 1];
    }
    float m = S * (1.f / 32768.f);
    float rstd = rsqrtf(SS * (1.f / 32768.f) - m * m + 1e-5f);
    float sw = w[c], sb = b[c];
    float4 v0 = ld4(&x0[(size_t)i << 2]);
    float4 v1 = ld4(&x1[(size_t)i << 2]);
    float r0 = fmaxf((v0.x + v1.x - m) * rstd * sw + sb, 0.f);
    float r1 = fmaxf((v0.y + v1.y - m) * rstd * sw + sb, 0.f);
    float r2 = fmaxf((v0.z + v1.z - m) * rstd * sw + sb, 0.f);
    float r3 = fmaxf((v0.w + v1.w - m) * rstd * sw + sb, 0.f);
    if (OUT == 0) {
        int px0 = (i & 1023) << 2;
        ob[(size_t)(px0 + 0) * 256 + c] = f2bf(r0);
        ob[(size_t)(px0 + 1) * 256 + c] = f2bf(r1);
        ob[(size_t)(px0 + 2) * 256 + c] = f2bf(r2);
        ob[(size_t)(px0 + 3) * 256 + c] = f2bf(r3);
    } else {
        float4 r = make_float4(r0, r1, r2, r3);
        *(float4*)&of[(size_t)i << 2] = r;
    }
}

// ---------------- host launcher ----------------
extern "C" void kernel_launch(void* const* d_in, const int* in_sizes, int n_in,
                              void* d_out, int out_size, void* d_ws, size_t ws_size,
                              hipStream_t stream)
{
    (void)in_sizes; (void)n_in; (void)out_size; (void)ws_size;
    const float* feat0 = (const float*)d_in[0];
    const float* feat1 = (const float*)d_in[1];
    const float* feat2 = (const float*)d_in[2];
    const float* in0_w = (const float*)d_in[3];
    const float* in0_b = (const float*)d_in[4];
    const float* in1_w = (const float*)d_in[5];
    const float* in1_b = (const float*)d_in[6];
    const float* in2_w = (const float*)d_in[7];
    const float* in2_b = (const float*)d_in[8];
    const float* off_w = (const float*)d_in[9];
    const float* off_b = (const float*)d_in[10];
    const float* aw_w  = (const float*)d_in[11];
    const float* aw_b  = (const float*)d_in[12];
    const float* vp_w  = (const float*)d_in[13];
    const float* vp_b  = (const float*)d_in[14];
    const float* op_w  = (const float*)d_in[15];
    const float* op_b  = (const float*)d_in[16];
    const float* n1_w  = (const float*)d_in[17];
    const float* n1_b  = (const float*)d_in[18];
    const float* ff1_w = (const float*)d_in[19];
    const float* ff1_b = (const float*)d_in[20];
    const float* ff2_w = (const float*)d_in[21];
    const float* ff2_b = (const float*)d_in[22];
    const float* n2_w  = (const float*)d_in[23];
    const float* n2_b  = (const float*)d_in[24];
    const float* fn_w  = (const float*)d_in[25];
    const float* fn_b  = (const float*)d_in[26];
    const float* lat_w = (const float*)d_in[27];
    const float* lat_b = (const float*)d_in[28];
    const float* out_w = (const float*)d_in[29];
    const float* gnw   = (const float*)d_in[30];
    const float* gnb   = (const float*)d_in[31];
    float* out = (float*)d_out;

    // ---- workspace (~63.9 MB; proven-safe layout) ----
    float* ws     = (float*)d_ws;
    float* src    = ws;                 // 1376256
    float* pos    = src  + 1376256;     // 1376256 (pong alias after encoder)
    float* tmp    = pos  + 1376256;     // 1376256 (pong2 alias after encoder)
    float* valbuf = tmp  + 1376256;     // 1376256 (valb bf16 | latb bf16)
    float* oab    = valbuf + 1376256;   // 1548288
    float* stats  = oab  + 1548288;     // 512 (gn slice partials)
    float* boa    = stats + 512;        // 1728
    float* zbuf   = boa  + 1728;        // 512 (zeros, covers N=288 bias)
    float* tmp2   = zbuf + 512;         // 1376256 (split-K partial)
    float* pong   = pos;                // conv partial 0
    float* pong2  = tmp;                // conv partial 1

    unsigned short* valb = (unsigned short*)valbuf;
    unsigned short* latb = (unsigned short*)(valbuf + 688128);

    unsigned short* ub = (unsigned short*)(tmp2 + 1376256);
    unsigned short* srcb  = ub; ub += 1376256;
    unsigned short* qbb   = ub; ub += 1376256;  // pingb alias after encoder
    unsigned short* msdb  = ub; ub += 1376256;
    unsigned short* ffhb  = ub; ub += 5505024;  // hosts fT0/1/2 during setup; oab2 during oavp/msdef
    unsigned short* w_oa  = ub; ub += 442368;
    unsigned short* w_vp  = ub; ub += 393216;   // contiguous run for cvtall:
    unsigned short* w_op  = ub; ub += 393216;   //   vp|op|ff1|ff2|in0|in1|in2|lat
    unsigned short* w_ff1 = ub; ub += 1572864;
    unsigned short* w_ff2 = ub; ub += 1572864;
    unsigned short* w_in0 = ub; ub += 65536;
    unsigned short* w_in1 = ub; ub += 131072;
    unsigned short* w_in2 = ub; ub += 262144;
    unsigned short* w_lat = ub; ub += 65536;
    unsigned short* wcb   = ub; ub += 1769472;

    unsigned short* fT0 = ffhb;
    unsigned short* fT1 = ffhb + 1048576;
    unsigned short* fT2 = ffhb + 1572864;
    unsigned short* pingb = qbb;
    // oab2 aliases ffhb: live only oavp->msdef (ffhb dead there: ff2(i-1) already read it,
    // ff1(i) writes after msdef(i) consumed oab2). 1548288 floats = 3096576 shorts < 5505024. 16B-aligned.
    float* oab2 = (float*)ffhb;

    // ---- setup (2 dispatches) ----
    setup_k<<<17472, 256, 0, stream>>>(off_w, off_b, aw_w, aw_b, w_oa, boa,
                                       out_w, wcb,
                                       vp_w, op_w, ff1_w, ff2_w, in0_w, in1_w, in2_w, lat_w, w_vp,
                                       pos,
                                       feat0, feat1, feat2, fT0, fT1, fT2, zbuf);

    // ---- input projections (fused; also emits qbb = src + pos) ----
    inproj_k<<<dim3(4, 84), 256, 0, stream>>>(fT0, w_in0, in0_b, fT1, w_in1, in1_b,
                                              fT2, w_in2, in2_b, src, srcb, pos, qbb);

    // ---- encoder layers (7 dispatches each) ----
    for (int i = 0; i < 6; i++) {
        oavp_k<<<dim3(14, 84), 256, 0, stream>>>(qbb, w_oa + i*73728, boa + i*288, zbuf,
                                                 oab, oab2,
                                                 srcb, w_vp + i*65536, vp_b + i*256, valb);
        msdef_k<<<1344, 256, 0, stream>>>(valb, oab, oab2, msdb);
        bgemmsk_k<<<dim3(4, 84, 2), 256, 0, stream>>>(msdb, w_op + i*65536, op_b + i*256, zbuf,
                                                      tmp, tmp2, 256, 256);
        ln_k<false><<<1344, 256, 0, stream>>>(src, tmp, tmp2, n1_w + i*256, n1_b + i*256,
                                              srcb, nullptr, nullptr);
        bgemm_k<<<dim3(16, 84), 256, 0, stream>>>(srcb, w_ff1 + i*262144, ff1_b + i*1024,
                                                  nullptr, ffhb, 1024, 256, 1, 1);
        bgemmsk_k<<<dim3(4, 84, 2), 256, 0, stream>>>(ffhb, w_ff2 + i*262144, ff2_b + i*256, zbuf,
                                                      tmp, tmp2, 256, 1024);
        if (i < 5)
            ln_k<true><<<1344, 256, 0, stream>>>(src, tmp, tmp2, n2_w + i*256, n2_b + i*256,
                                                 srcb, pos, qbb);
        else
            ln2fn_k<<<1344, 256, 0, stream>>>(src, tmp, tmp2, n2_w + i*256, n2_b + i*256,
                                              fn_w, fn_b, srcb);
    }

    // ---- mems transposes + lateral 1x1, one dispatch ----
    tail_k<<<1600, 256, 0, stream>>>(src, out + 1048576, srcb, w_lat, lat_b, latb);

    // ---- 3x (conv3x3 MFMA split-K z=2 -> gn stats (256 blk) -> gn apply (1024 blk)) ----
    conv3b_k<<<dim3(64, 8, 2), 256, 0, stream>>>(latb, wcb, pong, pong2);
    gnstats2_k<<<256, 256, 0, stream>>>(pong, pong2, stats);
    gnapply2_k<0><<<1024, 256, 0, stream>>>(pong, pong2, stats, gnw, gnb, pingb, nullptr);

    conv3b_k<<<dim3(64, 8, 2), 256, 0, stream>>>(pingb, wcb + 589824, pong, pong2);
    gnstats2_k<<<256, 256, 0, stream>>>(pong, pong2, stats);
    gnapply2_k<0><<<1024, 256, 0, stream>>>(pong, pong2, stats, gnw + 256, gnb + 256, pingb, nullptr);

    conv3b_k<<<dim3(64, 8, 2), 256, 0, stream>>>(pingb, wcb + 1179648, pong, pong2);
    gnstats2_k<<<256, 256, 0, stream>>>(pong, pong2, stats);
    gnapply2_k<1><<<1024, 256, 0, stream>>>(pong, pong2, stats, gnw + 512, gnb + 512, nullptr, out);
}

// Round 17
// 530.938 us; speedup vs baseline: 1.0267x; 1.0267x over previous
//
#include <hip/hip_runtime.h>
#include <math.h>

#define LTOT 5376

typedef __attribute__((ext_vector_type(8))) __bf16 bf16x8;
typedef __attribute__((ext_vector_type(4))) float f32x4;
typedef __attribute__((ext_vector_type(8))) unsigned short us8;
typedef __attribute__((ext_vector_type(4))) unsigned short us4;

static __device__ __forceinline__ float4 ld4(const float* p) { return *(const float4*)p; }

static __device__ __forceinline__ unsigned short f2bf(float f) {
    unsigned int u = __float_as_uint(f);
    return (unsigned short)((u + 0x7fffu + ((u >> 16) & 1u)) >> 16);
}
static __device__ __forceinline__ float bf2f(unsigned short s) {
    return __uint_as_float(((unsigned int)s) << 16);
}

// async global->LDS, 16B per lane; lds base wave-uniform (HW adds lane*16)
static __device__ __forceinline__ void gl16(const unsigned short* g, unsigned short* l) {
    __builtin_amdgcn_global_load_lds(
        (const __attribute__((address_space(1))) unsigned int*)g,
        (__attribute__((address_space(3))) unsigned int*)l, 16, 0, 0);
}

// ================= bf16 MFMA GEMM core, 3-buffer counted-vmcnt pipeline =================
__device__ __forceinline__ void gemm_core(
    const unsigned short* __restrict__ A,
    const unsigned short* __restrict__ B,
    const float* __restrict__ bias,
    float* __restrict__ C1, unsigned short* __restrict__ C2,
    const float* __restrict__ posf, unsigned short* __restrict__ qb,
    unsigned short* As, unsigned short* Bs,     // each 3*4096 shorts
    int m0, int mo0, int n0, int N, int Kloop, int ldk, int omode, int relu)
{
    const int tid  = threadIdx.x;
    const int wave = tid >> 6;
    const int lane = tid & 63;
    const int wm   = (wave >> 1) * 32;
    const int wn   = (wave & 1) * 32;
    const int fr   = lane & 15;
    const int ko   = lane >> 4;

    const int q0 = tid, q1 = tid + 256;
    const int r0 = q0 >> 3, c0v = (q0 & 7) ^ (r0 & 7);
    const int r1 = q1 >> 3, c1v = (q1 & 7) ^ (r1 & 7);
    const unsigned short* a0 = A + (size_t)(m0 + r0) * ldk + (c0v << 3);
    const unsigned short* a1 = A + (size_t)(m0 + r1) * ldk + (c1v << 3);
    int bn0 = n0 + r0; if (bn0 > N - 1) bn0 = N - 1;
    int bn1 = n0 + r1; if (bn1 > N - 1) bn1 = N - 1;
    const unsigned short* b0 = B + (size_t)bn0 * ldk + (c0v << 3);
    const unsigned short* b1 = B + (size_t)bn1 * ldk + (c1v << 3);
    const int wb = wave << 9;

    f32x4 acc[2][2] = {};
    const int nt = Kloop >> 6;

    auto stage = [&](int buf, int t) {
        const int kof = t << 6;
        gl16(a0 + kof, As + buf * 4096 + wb);
        gl16(a1 + kof, As + buf * 4096 + 2048 + wb);
        gl16(b0 + kof, Bs + buf * 4096 + wb);
        gl16(b1 + kof, Bs + buf * 4096 + 2048 + wb);
    };

    stage(0, 0);
    stage(1, 1);
    asm volatile("s_waitcnt vmcnt(4)" ::: "memory");
    __builtin_amdgcn_s_barrier();
    __builtin_amdgcn_sched_barrier(0);

    for (int t = 0; t < nt; t++) {
        if (t + 2 < nt) stage((t + 2) % 3, t + 2);
        const unsigned short* Ab = As + (t % 3) * 4096;
        const unsigned short* Bb = Bs + (t % 3) * 4096;
        #pragma unroll
        for (int sub = 0; sub < 2; sub++) {
            bf16x8 af[2], bfr[2];
            const int kk = (sub << 2) + ko;
            #pragma unroll
            for (int i = 0; i < 2; i++) {
                int r = wm + i * 16 + fr;
                af[i] = *(const bf16x8*)&Ab[(r << 6) + ((kk ^ (r & 7)) << 3)];
                int c = wn + i * 16 + fr;
                bfr[i] = *(const bf16x8*)&Bb[(c << 6) + ((kk ^ (c & 7)) << 3)];
            }
            #pragma unroll
            for (int i = 0; i < 2; i++)
                #pragma unroll
                for (int j = 0; j < 2; j++)
                    acc[i][j] = __builtin_amdgcn_mfma_f32_16x16x32_bf16(af[i], bfr[j], acc[i][j], 0, 0, 0);
        }
        if (t + 1 < nt) {
            if (t + 2 < nt) asm volatile("s_waitcnt vmcnt(4) lgkmcnt(0)" ::: "memory");
            else            asm volatile("s_waitcnt vmcnt(0) lgkmcnt(0)" ::: "memory");
            __builtin_amdgcn_s_barrier();
            __builtin_amdgcn_sched_barrier(0);
        }
    }

    #pragma unroll
    for (int j = 0; j < 2; j++) {
        int col = n0 + wn + j * 16 + fr;
        if (col >= N) continue;
        float cb = bias[col];
        #pragma unroll
        for (int i = 0; i < 2; i++) {
            #pragma unroll
            for (int r = 0; r < 4; r++) {
                int row = mo0 + wm + i * 16 + ko * 4 + r;
                float v = acc[i][j][r] + cb;
                if (relu) v = fmaxf(v, 0.f);
                size_t off = (size_t)row * N + col;
                if (omode == 0)      C1[off] = v;
                else if (omode == 1) C2[off] = f2bf(v);
                else if (omode == 2) { C1[off] = v; C2[off] = f2bf(v); }
                else { C1[off] = v; C2[off] = f2bf(v); qb[off] = f2bf(v + posf[off]); }
            }
        }
    }
}

// generic wrapper
__global__ __launch_bounds__(256) void bgemm_k(
    const unsigned short* __restrict__ A, const unsigned short* __restrict__ B,
    const float* __restrict__ bias, float* __restrict__ C1, unsigned short* __restrict__ C2,
    int N, int K, int omode, int relu)
{
    __shared__ unsigned short As[3 * 4096], Bs[3 * 4096];
    int m = blockIdx.y * 64;
    gemm_core(A, B, bias, C1, C2, nullptr, nullptr, As, Bs, m, m, blockIdx.x * 64, N, K, K, omode, relu);
}

// split-K (2-way) f32-out GEMM: kpart=blockIdx.z; partials to C0 / C1p
__global__ __launch_bounds__(256) void bgemmsk_k(
    const unsigned short* __restrict__ A, const unsigned short* __restrict__ B,
    const float* __restrict__ bias, const float* __restrict__ zbuf,
    float* __restrict__ C0, float* __restrict__ C1p, int N, int fullK)
{
    __shared__ unsigned short As[3 * 4096], Bs[3 * 4096];
    const int m = blockIdx.y * 64;
    const int kp = blockIdx.z;
    const int Ks = fullK >> 1;
    gemm_core(A + kp * Ks, B + kp * Ks, kp ? zbuf : bias,
              kp ? C1p : C0, nullptr, nullptr, nullptr,
              As, Bs, m, m, blockIdx.x * 64, N, Ks, fullK, 0, 0);
}

// fused per-layer head: oa-gemm (qbb -> oab, N=288) + vp-gemm (srcb -> valb, N=256)
__global__ __launch_bounds__(256) void oavp_k(
    const unsigned short* __restrict__ qbb, const unsigned short* __restrict__ woa,
    const float* __restrict__ boa, float* __restrict__ oab,
    const unsigned short* __restrict__ srcb, const unsigned short* __restrict__ wvp,
    const float* __restrict__ bvp, unsigned short* __restrict__ valb)
{
    __shared__ unsigned short As[3 * 4096], Bs[3 * 4096];
    const int bx = blockIdx.x;
    const int m = blockIdx.y * 64;
    if (bx < 5)
        gemm_core(qbb,  woa, boa, oab, nullptr, nullptr, nullptr, As, Bs, m, m, bx * 64, 288, 256, 256, 0, 0);
    else
        gemm_core(srcb, wvp, bvp, nullptr, valb, nullptr, nullptr, As, Bs, m, m, (bx - 5) * 64, 256, 256, 256, 1, 0);
}

// fused input projections (3 levels, different K) + qbb = src + pos epilogue
__global__ __launch_bounds__(256) void inproj_k(
    const unsigned short* __restrict__ fT0, const unsigned short* __restrict__ w0, const float* __restrict__ b0,
    const unsigned short* __restrict__ fT1, const unsigned short* __restrict__ w1, const float* __restrict__ b1,
    const unsigned short* __restrict__ fT2, const unsigned short* __restrict__ w2, const float* __restrict__ b2,
    float* __restrict__ src, unsigned short* __restrict__ srcb,
    const float* __restrict__ posf, unsigned short* __restrict__ qbb)
{
    __shared__ unsigned short As[3 * 4096], Bs[3 * 4096];
    const int by = blockIdx.y;
    const int n0 = blockIdx.x * 64;
    if (by < 64)
        gemm_core(fT0, w0, b0, src, srcb, posf, qbb, As, Bs, by * 64, by * 64, n0, 256, 256, 256, 3, 0);
    else if (by < 80)
        gemm_core(fT1, w1, b1, src, srcb, posf, qbb, As, Bs, (by - 64) * 64, 4096 + (by - 64) * 64, n0, 256, 512, 512, 3, 0);
    else
        gemm_core(fT2, w2, b2, src, srcb, posf, qbb, As, Bs, (by - 80) * 64, 5120 + (by - 80) * 64, n0, 256, 1024, 1024, 3, 0);
}

// ===== merged setup kernel (pack_oa | wconv | cvtall | posenc | cvtT feat0/1/2) =====
__global__ __launch_bounds__(256) void setup_k(
    const float* __restrict__ off_w, const float* __restrict__ off_b,
    const float* __restrict__ aw_w,  const float* __restrict__ aw_b,
    unsigned short* __restrict__ w_oa, float* __restrict__ b_oa,
    const float* __restrict__ out_w, unsigned short* __restrict__ wcb,
    const float* __restrict__ s0, const float* __restrict__ s1,
    const float* __restrict__ s2, const float* __restrict__ s3,
    const float* __restrict__ s4, const float* __restrict__ s5,
    const float* __restrict__ s6, const float* __restrict__ s7,
    unsigned short* __restrict__ dcvt,
    float* __restrict__ pos,
    const float* __restrict__ f0, const float* __restrict__ f1, const float* __restrict__ f2,
    unsigned short* __restrict__ d0, unsigned short* __restrict__ d1, unsigned short* __restrict__ d2,
    float* __restrict__ zbuf)
{
    const int bid = blockIdx.x;
    const int tid = threadIdx.x;
    if (bid < 1728) {
        int idx = bid * 256 + tid;
        int i = idx / 73728;
        int r = idx - i * 73728;
        int n = r >> 8;
        int k = r & 255;
        float v = (n < 192) ? off_w[((size_t)i * 192 + n) * 256 + k]
                            : aw_w[((size_t)i * 96 + (n - 192)) * 256 + k];
        w_oa[idx] = f2bf(v);
        if (k == 0)
            b_oa[i * 288 + n] = (n < 192) ? off_b[i * 192 + n] : aw_b[i * 96 + (n - 192)];
        if (bid == 0) zbuf[tid] = 0.f;
    } else if (bid < 8640) {
        int idx = (bid - 1728) * 256 + tid;
        int c   = idx / 589824;
        int r   = idx - c * 589824;
        int icc = r / 73728;
        int r2  = r - icc * 73728;
        int oc  = r2 / 288;
        int r3  = r2 - oc * 288;
        int tap = r3 >> 5;
        int sl  = r3 & 31;
        int ic  = icc * 32 + (((sl >> 3) ^ ((oc >> 1) & 3)) << 3) + (sl & 7);
        wcb[idx] = f2bf(out_w[(((size_t)(c * 256 + oc)) * 256 + ic) * 9 + tap]);
    } else if (bid < 12992) {
        int i = (bid - 8640) * 256 + tid;
        const float* s; int off;
        if      (i <   98304) { s = s0; off = 0; }
        else if (i <  196608) { s = s1; off = 98304; }
        else if (i <  589824) { s = s2; off = 196608; }
        else if (i <  983040) { s = s3; off = 589824; }
        else if (i <  999424) { s = s4; off = 983040; }
        else if (i < 1032192) { s = s5; off = 999424; }
        else if (i < 1097728) { s = s6; off = 1032192; }
        else                  { s = s7; off = 1097728; }
        float4 v = ld4(&s[(size_t)(i - off) << 2]);
        us4 r = { f2bf(v.x), f2bf(v.y), f2bf(v.z), f2bf(v.w) };
        *(us4*)&dcvt[(size_t)i << 2] = r;
    } else if (bid < 15680) {
        int idx = (bid - 12992) * 256 + tid;
        int l = idx >> 7;
        int pr = idx & 127;
        int half = pr >> 6;
        int j = pr & 63;
        int HW, sh, p;
        if (l < 4096)      { HW = 64; sh = 6; p = l; }
        else if (l < 5120) { HW = 32; sh = 5; p = l - 4096; }
        else               { HW = 16; sh = 4; p = l - 5120; }
        int y = p >> sh;
        int x = p & (HW - 1);
        float invT = exp2f((float)j * (-13.287712379549449f / 64.f));
        float coord = (half == 0) ? (float)(y + 1) : (float)(x + 1);
        float v = coord / ((float)HW + 1e-6f) * 6.283185307179586f;
        float arg = v * invT;
        size_t base = (size_t)l * 256 + half * 128 + (j << 1);
        pos[base]     = sinf(arg);
        pos[base + 1] = cosf(arg);
    } else {
        __shared__ float t[32][33];
        int b = bid - 15680;
        const float* src; unsigned short* dst; int Ci, P, bx, by;
        if (b < 1024)      { src = f0; dst = d0; Ci = 256;  P = 4096; bx = b & 127;        by = b >> 7; }
        else if (b < 1536) { src = f1; dst = d1; Ci = 512;  P = 1024; bx = (b - 1024) & 31; by = (b - 1024) >> 5; }
        else               { src = f2; dst = d2; Ci = 1024; P = 256;  bx = (b - 1536) & 7;  by = (b - 1536) >> 3; }
        int c0 = by * 32, p0 = bx * 32;
        int x = tid & 31, y = tid >> 5;
        for (int i = y; i < 32; i += 8)
            t[i][x] = src[(size_t)(c0 + i) * P + p0 + x];
        __syncthreads();
        for (int i = y; i < 32; i += 8)
            dst[(size_t)(p0 + i) * Ci + c0 + x] = f2bf(t[x][i]);
    }
}

// ---------------- multi-scale deformable sampling, softmax fused ----------------
// 4 positions/block, 64 thr/pos; thread: 1 head x 4 channels (us4 gathers). grid 1344.
__global__ __launch_bounds__(256) void msdef_k(
    const unsigned short* __restrict__ valb, const float* __restrict__ oab,
    unsigned short* __restrict__ out)
{
    __shared__ float sw[4 * 288];
    const int tid = threadIdx.x;
    const int bl = blockIdx.x;
    #pragma unroll
    for (int id = tid; id < 288; id += 256)
        ((float4*)sw)[id] = ((const float4*)(oab + (size_t)bl * 1152))[id];
    __syncthreads();

    const int p = tid >> 6;          // 0..3
    const int t = tid & 63;
    const int l = bl * 4 + p;
    const int h = t >> 3;            // 0..7
    const int co = (t & 7) << 2;     // 0,4,...,28
    const float* mo = sw + p * 288;

    float aw_r[12];
    {
        const float* sc = mo + 192 + h * 12;
        float mx = -1e30f;
        #pragma unroll
        for (int j = 0; j < 12; j++) { aw_r[j] = sc[j]; mx = fmaxf(mx, aw_r[j]); }
        float su = 0.f;
        #pragma unroll
        for (int j = 0; j < 12; j++) { aw_r[j] = expf(aw_r[j] - mx); su += aw_r[j]; }
        float inv = 1.f / su;
        #pragma unroll
        for (int j = 0; j < 12; j++) aw_r[j] *= inv;
    }

    float rx, ry;
    {
        int HW, sh, q;
        if (l < 4096)      { HW = 64; sh = 6; q = l; }
        else if (l < 5120) { HW = 32; sh = 5; q = l - 4096; }
        else               { HW = 16; sh = 4; q = l - 5120; }
        int y = q >> sh;
        int x = q & (HW - 1);
        rx = (x + 0.5f) / (float)HW;
        ry = (y + 0.5f) / (float)HW;
    }

    const int starts[3] = {0, 4096, 5120};
    const int dims[3]   = {64, 32, 16};
    float acc[4] = {};
    #pragma unroll
    for (int s = 0; s < 3; s++) {
        const int D = dims[s];
        const int st = starts[s];
        #pragma unroll
        for (int pt = 0; pt < 4; pt++) {
            float a  = aw_r[(s << 2) + pt];
            float px = rx * D + mo[h * 24 + (s << 3) + (pt << 1)]     - 0.5f;
            float py = ry * D + mo[h * 24 + (s << 3) + (pt << 1) + 1] - 0.5f;
            float x0f = floorf(px), y0f = floorf(py);
            float lx = px - x0f, ly = py - y0f;
            int x0 = (int)x0f, y0 = (int)y0f;
            float w00 = a * (1.f - lx) * (1.f - ly);
            float w10 = a * lx * (1.f - ly);
            float w01 = a * (1.f - lx) * ly;
            float w11 = a * lx * ly;
            #pragma unroll
            for (int cy = 0; cy < 2; cy++) {
                int yi = y0 + cy;
                if (yi < 0 || yi >= D) continue;
                #pragma unroll
                for (int cx = 0; cx < 2; cx++) {
                    int xi = x0 + cx;
                    if (xi < 0 || xi >= D) continue;
                    float w = cy ? (cx ? w11 : w01) : (cx ? w10 : w00);
                    us4 v = *(const us4*)&valb[((size_t)(st + yi * D + xi) << 8) + (h << 5) + co];
                    #pragma unroll
                    for (int e = 0; e < 4; e++)
                        acc[e] = fmaf(w, bf2f(v[e]), acc[e]);
                }
            }
        }
    }
    us4 r;
    #pragma unroll
    for (int e = 0; e < 4; e++) r[e] = f2bf(acc[e]);
    *(us4*)&out[((size_t)l << 8) + (h << 5) + co] = r;
}

// ---------------- layernorm (+2 residual partials), in-place fp32 + bf16 copy (+ q=out+pos) ----------------
template<bool HAS_POS>
__global__ __launch_bounds__(256) void ln_k(float* __restrict__ src, const float* __restrict__ add,
                                            const float* __restrict__ add2,
                                            const float* __restrict__ w, const float* __restrict__ b,
                                            unsigned short* __restrict__ outb,
                                            const float* __restrict__ posf,
                                            unsigned short* __restrict__ qbout)
{
    int row = blockIdx.x * 4 + (threadIdx.x >> 6);
    int lane = threadIdx.x & 63;
    size_t base = (size_t)row * 256 + (lane << 2);
    float4 x = ld4(&src[base]);
    float4 a = ld4(&add[base]);
    float4 a2 = ld4(&add2[base]);
    x.x += a.x + a2.x; x.y += a.y + a2.y; x.z += a.z + a2.z; x.w += a.w + a2.w;
    float s = x.x + x.y + x.z + x.w;
    #pragma unroll
    for (int o = 32; o > 0; o >>= 1) s += __shfl_xor(s, o, 64);
    float m = s * (1.f / 256.f);
    float d0 = x.x - m, d1 = x.y - m, d2 = x.z - m, d3 = x.w - m;
    float v = d0 * d0 + d1 * d1 + d2 * d2 + d3 * d3;
    #pragma unroll
    for (int o = 32; o > 0; o >>= 1) v += __shfl_xor(v, o, 64);
    float rs = rsqrtf(v * (1.f / 256.f) + 1e-5f);
    float4 wv = ld4(&w[lane << 2]);
    float4 bv = ld4(&b[lane << 2]);
    float4 o4;
    o4.x = d0 * rs * wv.x + bv.x;
    o4.y = d1 * rs * wv.y + bv.y;
    o4.z = d2 * rs * wv.z + bv.z;
    o4.w = d3 * rs * wv.w + bv.w;
    *(float4*)&src[base] = o4;
    us4 r = { f2bf(o4.x), f2bf(o4.y), f2bf(o4.z), f2bf(o4.w) };
    *(us4*)&outb[base] = r;
    if (HAS_POS) {
        float4 p4 = ld4(&posf[base]);
        us4 q = { f2bf(o4.x + p4.x), f2bf(o4.y + p4.y), f2bf(o4.z + p4.z), f2bf(o4.w + p4.w) };
        *(us4*)&qbout[base] = q;
    }
}

// ---------------- layer-5 ln2 + final fn layernorm fused (two LN passes) ----------------
__global__ __launch_bounds__(256) void ln2fn_k(float* __restrict__ src, const float* __restrict__ add,
                                               const float* __restrict__ add2,
                                               const float* __restrict__ w2, const float* __restrict__ b2,
                                               const float* __restrict__ wf, const float* __restrict__ bf,
                                               unsigned short* __restrict__ outb)
{
    int row = blockIdx.x * 4 + (threadIdx.x >> 6);
    int lane = threadIdx.x & 63;
    size_t base = (size_t)row * 256 + (lane << 2);
    float4 x = ld4(&src[base]);
    float4 a = ld4(&add[base]);
    float4 a2 = ld4(&add2[base]);
    x.x += a.x + a2.x; x.y += a.y + a2.y; x.z += a.z + a2.z; x.w += a.w + a2.w;
    // pass 1: n2
    float s = x.x + x.y + x.z + x.w;
    #pragma unroll
    for (int o = 32; o > 0; o >>= 1) s += __shfl_xor(s, o, 64);
    float m = s * (1.f / 256.f);
    float d0 = x.x - m, d1 = x.y - m, d2 = x.z - m, d3 = x.w - m;
    float v = d0 * d0 + d1 * d1 + d2 * d2 + d3 * d3;
    #pragma unroll
    for (int o = 32; o > 0; o >>= 1) v += __shfl_xor(v, o, 64);
    float rs = rsqrtf(v * (1.f / 256.f) + 1e-5f);
    float4 wv = ld4(&w2[lane << 2]);
    float4 bv = ld4(&b2[lane << 2]);
    float4 o4;
    o4.x = d0 * rs * wv.x + bv.x;
    o4.y = d1 * rs * wv.y + bv.y;
    o4.z = d2 * rs * wv.z + bv.z;
    o4.w = d3 * rs * wv.w + bv.w;
    // pass 2: fn
    float s2 = o4.x + o4.y + o4.z + o4.w;
    #pragma unroll
    for (int o = 32; o > 0; o >>= 1) s2 += __shfl_xor(s2, o, 64);
    float m2 = s2 * (1.f / 256.f);
    float e0 = o4.x - m2, e1 = o4.y - m2, e2 = o4.z - m2, e3 = o4.w - m2;
    float v2 = e0 * e0 + e1 * e1 + e2 * e2 + e3 * e3;
    #pragma unroll
    for (int o = 32; o > 0; o >>= 1) v2 += __shfl_xor(v2, o, 64);
    float rs2 = rsqrtf(v2 * (1.f / 256.f) + 1e-5f);
    float4 wf4 = ld4(&wf[lane << 2]);
    float4 bf4 = ld4(&bf[lane << 2]);
    float4 o5;
    o5.x = e0 * rs2 * wf4.x + bf4.x;
    o5.y = e1 * rs2 * wf4.y + bf4.y;
    o5.z = e2 * rs2 * wf4.z + bf4.z;
    o5.w = e3 * rs2 * wf4.w + bf4.w;
    *(float4*)&src[base] = o5;
    us4 r = { f2bf(o5.x), f2bf(o5.y), f2bf(o5.z), f2bf(o5.w) };
    *(us4*)&outb[base] = r;
}

// ===== tail: mems transposes (3 levels) + lateral 1x1 GEMM, one dispatch =====
__global__ __launch_bounds__(256) void tail_k(
    const float* __restrict__ src, float* __restrict__ outb_,
    const unsigned short* __restrict__ srcb, const unsigned short* __restrict__ w_lat,
    const float* __restrict__ lat_b, unsigned short* __restrict__ latb)
{
    if (blockIdx.x < 1344) {
        __shared__ float t[32][33];
        int b = blockIdx.x;
        int bx = b % 168, cy = b / 168;
        const float* s; float* d; int HW, p0;
        if (bx < 128)      { s = src;           d = outb_;           HW = 4096; p0 = bx * 32; }
        else if (bx < 160) { s = src + 1048576; d = outb_ + 1048576; HW = 1024; p0 = (bx - 128) * 32; }
        else               { s = src + 1310720; d = outb_ + 1310720; HW = 256;  p0 = (bx - 160) * 32; }
        int c0 = cy * 32;
        int x = threadIdx.x & 31, y = threadIdx.x >> 5;
        for (int i = y; i < 32; i += 8)
            t[i][x] = s[(size_t)(p0 + i) * 256 + c0 + x];
        __syncthreads();
        for (int i = y; i < 32; i += 8)
            d[(size_t)(c0 + i) * HW + p0 + x] = t[x][i];
    } else {
        __shared__ unsigned short As[3 * 4096], Bs[3 * 4096];
        int b = blockIdx.x - 1344;
        int m = (b >> 2) * 64;
        gemm_core(srcb, w_lat, lat_b, nullptr, latb, nullptr, nullptr, As, Bs,
                  m, m, (b & 3) * 64, 256, 256, 256, 1, 0);
    }
}

// ---------------- 3x3 conv via bf16 MFMA implicit GEMM, icc split-K (z=2) ----------------
__global__ __launch_bounds__(256) void conv3b_k(const unsigned short* __restrict__ inb,
                                                const unsigned short* __restrict__ wcb,
                                                float* __restrict__ out0,
                                                float* __restrict__ out1)
{
    __shared__ __align__(16) unsigned char smem[25344];
    unsigned short* sIn = (unsigned short*)smem;
    unsigned short* sW  = (unsigned short*)(smem + 6912);
    float* sO = (float*)smem;

    const int tid = threadIdx.x;
    const int mb = blockIdx.x;
    const int y0 = (mb >> 2) << 2;
    const int x0 = (mb & 3) << 4;
    const int oc0 = blockIdx.y << 5;
    const int icc0 = blockIdx.z << 2;
    float* out = blockIdx.z ? out1 : out0;
    const int wave = tid >> 6, lane = tid & 63;
    const int wm = (wave >> 1) * 32;
    const int wn = (wave & 1) * 16;
    const int fr = lane & 15, ko = lane >> 4;

    f32x4 acc[2] = {};

    for (int icc = icc0; icc < icc0 + 4; icc++) {
        __syncthreads();
        #pragma unroll
        for (int id = tid; id < 432; id += 256) {
            int pxi = id >> 2, ch = id & 3;
            int r = pxi / 18, s = pxi - r * 18;
            int gy = y0 - 1 + r, gx = x0 - 1 + s;
            us8 v = {};
            if (gy >= 0 && gy < 64 && gx >= 0 && gx < 64)
                v = *(const us8*)&inb[((size_t)(gy * 64 + gx) << 8) + (icc << 5) + (ch << 3)];
            *(us8*)&sIn[(pxi << 5) + ((ch ^ ((s >> 1) & 3)) << 3)] = v;
        }
        const unsigned short* wsrc = wcb + (((size_t)icc * 256 + oc0) * 9 << 5);
        #pragma unroll
        for (int id = tid; id < 1152; id += 256)
            *(us8*)&sW[id << 3] = *(const us8*)&wsrc[id << 3];
        __syncthreads();

        #pragma unroll
        for (int tap = 0; tap < 9; tap++) {
            const int ky = tap / 3, kx = tap - ky * 3;
            bf16x8 a[2], b;
            #pragma unroll
            for (int i = 0; i < 2; i++) {
                int px = wm + i * 16 + fr;
                int r = (px >> 4) + ky;
                int s = (px & 15) + kx;
                a[i] = *(const bf16x8*)&sIn[(((r * 18 + s)) << 5) + ((ko ^ ((s >> 1) & 3)) << 3)];
            }
            {
                int oc = wn + fr;
                b = *(const bf16x8*)&sW[(((oc * 9) + tap) << 5) + ((ko ^ ((oc >> 1) & 3)) << 3)];
            }
            #pragma unroll
            for (int i = 0; i < 2; i++)
                acc[i] = __builtin_amdgcn_mfma_f32_16x16x32_bf16(a[i], b, acc[i], 0, 0, 0);
        }
    }

    __syncthreads();
    #pragma unroll
    for (int i = 0; i < 2; i++) {
        int oc = wn + fr;
        int pxb = wm + i * 16 + ko * 4;
        *(f32x4*)&sO[oc * 68 + pxb] = acc[i];
    }
    __syncthreads();
    {
        int oc_r = tid >> 3;
        int yy   = (tid >> 1) & 3;
        int xh   = (tid & 1) << 3;
        float* dst = &out[(size_t)(oc0 + oc_r) * 4096 + (y0 + yy) * 64 + x0 + xh];
        const float* srcl = &sO[oc_r * 68 + yy * 16 + xh];
        *(float4*)&dst[0] = *(const float4*)&srcl[0];
        *(float4*)&dst[4] = *(const float4*)&srcl[4];
    }
}

// ---------------- groupnorm stage 1: per-slice partial stats (256 blocks) ----------------
__global__ __launch_bounds__(256) void gnstats2_k(const float* __restrict__ x0,
                                                  const float* __restrict__ x1,
                                                  float* __restrict__ st)
{
    const int g  = blockIdx.x >> 3;
    const int sl = blockIdx.x & 7;
    const float* p0 = x0 + (size_t)g * 32768 + sl * 4096;
    const float* p1 = x1 + (size_t)g * 32768 + sl * 4096;
    float s = 0.f, ss = 0.f;
    #pragma unroll
    for (int i = threadIdx.x * 4; i < 4096; i += 1024) {
        float4 v0 = ld4(&p0[i]);
        float4 v1 = ld4(&p1[i]);
        float e0 = v0.x + v1.x, e1 = v0.y + v1.y, e2 = v0.z + v1.z, e3 = v0.w + v1.w;
        s  += e0 + e1 + e2 + e3;
        ss += e0 * e0 + e1 * e1 + e2 * e2 + e3 * e3;
    }
    #pragma unroll
    for (int o = 32; o > 0; o >>= 1) {
        s  += __shfl_xor(s, o, 64);
        ss += __shfl_xor(ss, o, 64);
    }
    __shared__ float rs[4], rss[4];
    int wid = threadIdx.x >> 6;
    if ((threadIdx.x & 63) == 0) { rs[wid] = s; rss[wid] = ss; }
    __syncthreads();
    if (threadIdx.x == 0) {
        st[blockIdx.x * 2]     = rs[0] + rs[1] + rs[2] + rs[3];
        st[blockIdx.x * 2 + 1] = rss[0] + rss[1] + rss[2] + rss[3];
    }
}

// ---------------- groupnorm stage 2: apply + relu (1024 blocks) ----------------
template<int OUT>
__global__ __launch_bounds__(256) void gnapply2_k(const float* __restrict__ x0,
                                                  const float* __restrict__ x1,
                                                  const float* __restrict__ st,
                                                  const float* __restrict__ w, const float* __restrict__ b,
                                                  unsigned short* __restrict__ ob, float* __restrict__ of)
{
    int i = blockIdx.x * 256 + threadIdx.x;   // float4 index, 262144 total
    int c = i >> 10;
    int g = c >> 3;
    float S = 0.f, SS = 0.f;
    #pragma unroll
    for (int k = 0; k < 8; k++) {
        S  += st[(g * 8 + k) * 2];
        SS += st[(g * 8 + k) * 2 + 1];
    }
    float m = S * (1.f / 32768.f);
    float rstd = rsqrtf(SS * (1.f / 32768.f) - m * m + 1e-5f);
    float sw = w[c], sb = b[c];
    float4 v0 = ld4(&x0[(size_t)i << 2]);
    float4 v1 = ld4(&x1[(size_t)i << 2]);
    float r0 = fmaxf((v0.x + v1.x - m) * rstd * sw + sb, 0.f);
    float r1 = fmaxf((v0.y + v1.y - m) * rstd * sw + sb, 0.f);
    float r2 = fmaxf((v0.z + v1.z - m) * rstd * sw + sb, 0.f);
    float r3 = fmaxf((v0.w + v1.w - m) * rstd * sw + sb, 0.f);
    if (OUT == 0) {
        int px0 = (i & 1023) << 2;
        ob[(size_t)(px0 + 0) * 256 + c] = f2bf(r0);
        ob[(size_t)(px0 + 1) * 256 + c] = f2bf(r1);
        ob[(size_t)(px0 + 2) * 256 + c] = f2bf(r2);
        ob[(size_t)(px0 + 3) * 256 + c] = f2bf(r3);
    } else {
        float4 r = make_float4(r0, r1, r2, r3);
        *(float4*)&of[(size_t)i << 2] = r;
    }
}

// ---------------- host launcher ----------------
extern "C" void kernel_launch(void* const* d_in, const int* in_sizes, int n_in,
                              void* d_out, int out_size, void* d_ws, size_t ws_size,
                              hipStream_t stream)
{
    (void)in_sizes; (void)n_in; (void)out_size; (void)ws_size;
    const float* feat0 = (const float*)d_in[0];
    const float* feat1 = (const float*)d_in[1];
    const float* feat2 = (const float*)d_in[2];
    const float* in0_w = (const float*)d_in[3];
    const float* in0_b = (const float*)d_in[4];
    const float* in1_w = (const float*)d_in[5];
    const float* in1_b = (const float*)d_in[6];
    const float* in2_w = (const float*)d_in[7];
    const float* in2_b = (const float*)d_in[8];
    const float* off_w = (const float*)d_in[9];
    const float* off_b = (const float*)d_in[10];
    const float* aw_w  = (const float*)d_in[11];
    const float* aw_b  = (const float*)d_in[12];
    const float* vp_w  = (const float*)d_in[13];
    const float* vp_b  = (const float*)d_in[14];
    const float* op_w  = (const float*)d_in[15];
    const float* op_b  = (const float*)d_in[16];
    const float* n1_w  = (const float*)d_in[17];
    const float* n1_b  = (const float*)d_in[18];
    const float* ff1_w = (const float*)d_in[19];
    const float* ff1_b = (const float*)d_in[20];
    const float* ff2_w = (const float*)d_in[21];
    const float* ff2_b = (const float*)d_in[22];
    const float* n2_w  = (const float*)d_in[23];
    const float* n2_b  = (const float*)d_in[24];
    const float* fn_w  = (const float*)d_in[25];
    const float* fn_b  = (const float*)d_in[26];
    const float* lat_w = (const float*)d_in[27];
    const float* lat_b = (const float*)d_in[28];
    const float* out_w = (const float*)d_in[29];
    const float* gnw   = (const float*)d_in[30];
    const float* gnb   = (const float*)d_in[31];
    float* out = (float*)d_out;

    // ---- workspace (~63.9 MB) ----
    float* ws     = (float*)d_ws;
    float* src    = ws;                 // 1376256
    float* pos    = src  + 1376256;     // 1376256 (pong alias after encoder)
    float* tmp    = pos  + 1376256;     // 1376256 (pong2 alias after encoder)
    float* valbuf = tmp  + 1376256;     // 1376256 (valb bf16 | latb bf16)
    float* oab    = valbuf + 1376256;   // 1548288
    float* stats  = oab  + 1548288;     // 512 (gn slice partials)
    float* boa    = stats + 512;        // 1728
    float* zbuf   = boa  + 1728;        // 256
    float* tmp2   = zbuf + 256;         // 1376256 (split-K partial)
    float* pong   = pos;                // conv partial 0
    float* pong2  = tmp;                // conv partial 1

    unsigned short* valb = (unsigned short*)valbuf;
    unsigned short* latb = (unsigned short*)(valbuf + 688128);

    unsigned short* ub = (unsigned short*)(tmp2 + 1376256);
    unsigned short* srcb  = ub; ub += 1376256;
    unsigned short* qbb   = ub; ub += 1376256;  // pingb alias after encoder
    unsigned short* msdb  = ub; ub += 1376256;
    unsigned short* ffhb  = ub; ub += 5505024;  // hosts fT0/1/2 during setup
    unsigned short* w_oa  = ub; ub += 442368;
    unsigned short* w_vp  = ub; ub += 393216;   // contiguous run for cvtall:
    unsigned short* w_op  = ub; ub += 393216;   //   vp|op|ff1|ff2|in0|in1|in2|lat
    unsigned short* w_ff1 = ub; ub += 1572864;
    unsigned short* w_ff2 = ub; ub += 1572864;
    unsigned short* w_in0 = ub; ub += 65536;
    unsigned short* w_in1 = ub; ub += 131072;
    unsigned short* w_in2 = ub; ub += 262144;
    unsigned short* w_lat = ub; ub += 65536;
    unsigned short* wcb   = ub; ub += 1769472;

    unsigned short* fT0 = ffhb;
    unsigned short* fT1 = ffhb + 1048576;
    unsigned short* fT2 = ffhb + 1572864;
    unsigned short* pingb = qbb;

    // ---- setup (2 dispatches) ----
    setup_k<<<17472, 256, 0, stream>>>(off_w, off_b, aw_w, aw_b, w_oa, boa,
                                       out_w, wcb,
                                       vp_w, op_w, ff1_w, ff2_w, in0_w, in1_w, in2_w, lat_w, w_vp,
                                       pos,
                                       feat0, feat1, feat2, fT0, fT1, fT2, zbuf);

    // ---- input projections (fused; also emits qbb = src + pos) ----
    inproj_k<<<dim3(4, 84), 256, 0, stream>>>(fT0, w_in0, in0_b, fT1, w_in1, in1_b,
                                              fT2, w_in2, in2_b, src, srcb, pos, qbb);

    // ---- encoder layers (7 dispatches each) ----
    for (int i = 0; i < 6; i++) {
        oavp_k<<<dim3(9, 84), 256, 0, stream>>>(qbb, w_oa + i*73728, boa + i*288, oab,
                                                srcb, w_vp + i*65536, vp_b + i*256, valb);
        msdef_k<<<1344, 256, 0, stream>>>(valb, oab, msdb);
        bgemmsk_k<<<dim3(4, 84, 2), 256, 0, stream>>>(msdb, w_op + i*65536, op_b + i*256, zbuf,
                                                      tmp, tmp2, 256, 256);
        ln_k<false><<<1344, 256, 0, stream>>>(src, tmp, tmp2, n1_w + i*256, n1_b + i*256,
                                              srcb, nullptr, nullptr);
        bgemm_k<<<dim3(16, 84), 256, 0, stream>>>(srcb, w_ff1 + i*262144, ff1_b + i*1024,
                                                  nullptr, ffhb, 1024, 256, 1, 1);
        bgemmsk_k<<<dim3(4, 84, 2), 256, 0, stream>>>(ffhb, w_ff2 + i*262144, ff2_b + i*256, zbuf,
                                                      tmp, tmp2, 256, 1024);
        if (i < 5)
            ln_k<true><<<1344, 256, 0, stream>>>(src, tmp, tmp2, n2_w + i*256, n2_b + i*256,
                                                 srcb, pos, qbb);
        else
            ln2fn_k<<<1344, 256, 0, stream>>>(src, tmp, tmp2, n2_w + i*256, n2_b + i*256,
                                              fn_w, fn_b, srcb);
    }

    // ---- mems transposes + lateral 1x1, one dispatch ----
    tail_k<<<1600, 256, 0, stream>>>(src, out + 1048576, srcb, w_lat, lat_b, latb);

    // ---- 3x (conv3x3 MFMA split-K z=2 -> gn stats (256 blk) -> gn apply (1024 blk)) ----
    conv3b_k<<<dim3(64, 8, 2), 256, 0, stream>>>(latb, wcb, pong, pong2);
    gnstats2_k<<<256, 256, 0, stream>>>(pong, pong2, stats);
    gnapply2_k<0><<<1024, 256, 0, stream>>>(pong, pong2, stats, gnw, gnb, pingb, nullptr);

    conv3b_k<<<dim3(64, 8, 2), 256, 0, stream>>>(pingb, wcb + 589824, pong, pong2);
    gnstats2_k<<<256, 256, 0, stream>>>(pong, pong2, stats);
    gnapply2_k<0><<<1024, 256, 0, stream>>>(pong, pong2, stats, gnw + 256, gnb + 256, pingb, nullptr);

    conv3b_k<<<dim3(64, 8, 2), 256, 0, stream>>>(pingb, wcb + 1179648, pong, pong2);
    gnstats2_k<<<256, 256, 0, stream>>>(pong, pong2, stats);
    gnapply2_k<1><<<1024, 256, 0, stream>>>(pong, pong2, stats, gnw + 512, gnb + 512, nullptr, out);
}